// Round 4
// baseline (1394.594 us; speedup 1.0000x reference)
//
#include <hip/hip_runtime.h>
#include <hip/hip_bf16.h>

#define A_TOTAL 110484
#define NCLS 80
#define CAP 4096
#define MAX_DETS 100
#define IMGF 768.0f
#define IOU_T 0.2f

struct Ws {
    int count;
    int pad[3];
    float score[CAP];
    int anchor[CAP];
    int label[CAP];
    float4 box[CAP];
};

// LDS swizzle: lane-owned regions are 64 slots apart; rotate within-region index
// by owner lane so simultaneous per-lane accesses spread across banks instead of
// all landing in bank 0 (stride 512B/1024B == bank-0 aliasing otherwise).
__device__ __forceinline__ int swz(int s) {
    return (s & ~63) | (((s & 63) + (s >> 6)) & 63);
}

// Phase 1: 4 lanes per anchor. Lane sub in [0,4) reads quads {sub, sub+4, ..., sub+16}
// (64B stride -> each wave-load touches 16 fully-used contiguous 64B lines).
// Cross-lane max via monotone-float key with label tie-break (== jnp.argmax).
__global__ void score_decode_kernel(const float* __restrict__ cls,
                                    const float* __restrict__ reg,
                                    const float* __restrict__ anc,
                                    Ws* __restrict__ ws) {
    int gid = blockIdx.x * blockDim.x + threadIdx.x;
    int a = gid >> 2;
    int sub = gid & 3;
    if (a >= A_TOTAL) return;

    const float4* row = (const float4*)(cls + (size_t)a * NCLS);
    float m = -1e30f;
    int lbl = 0;
#pragma unroll
    for (int q = 0; q < 5; ++q) {
        float4 v = row[sub + q * 4];
        int c0 = (sub + q * 4) * 4;
        if (v.x > m) { m = v.x; lbl = c0 + 0; }
        if (v.y > m) { m = v.y; lbl = c0 + 1; }
        if (v.z > m) { m = v.z; lbl = c0 + 2; }
        if (v.w > m) { m = v.w; lbl = c0 + 3; }
    }

    // monotone mapping of float bits (handles negative logits), tie -> min label
    unsigned int mb = __float_as_uint(m);
    mb ^= (mb & 0x80000000u) ? 0xFFFFFFFFu : 0x80000000u;
    unsigned long long key =
        ((unsigned long long)mb << 32) | (unsigned int)(0xFFFFFFFFu - (unsigned int)lbl);
#pragma unroll
    for (int d = 1; d < 4; d <<= 1) {
        unsigned long long o = __shfl_xor(key, d, 64);
        if (o > key) key = o;
    }
    if (sub != 0) return;

    unsigned int hb = (unsigned int)(key >> 32);
    hb ^= (hb & 0x80000000u) ? 0x80000000u : 0xFFFFFFFFu;  // inverse map -> exact m
    m = __uint_as_float(hb);
    lbl = (int)(0xFFFFFFFFu - (unsigned int)(key & 0xFFFFFFFFu));

    float sig = 1.0f / (1.0f + expf(-m));
    if (!(sig > 0.2f)) return;

    // decode (no FMA contraction: match numpy's separate roundings) — identical
    // to the round-0 kernel that validated with absmax 0.0
    float4 ab = ((const float4*)anc)[a];  // y1,x1,y2,x2
    float4 rb = ((const float4*)reg)[a];  // dy,dx,dh,dw
    float ya = __fmul_rn(__fadd_rn(ab.x, ab.z), 0.5f);
    float xa = __fmul_rn(__fadd_rn(ab.y, ab.w), 0.5f);
    float ha = __fsub_rn(ab.z, ab.x);
    float wa = __fsub_rn(ab.w, ab.y);
    float w = __fmul_rn(expf(rb.w), wa);
    float h = __fmul_rn(expf(rb.z), ha);
    float yc = __fadd_rn(__fmul_rn(rb.x, ha), ya);
    float xc = __fadd_rn(__fmul_rn(rb.y, wa), xa);
    float x1 = fmaxf(__fsub_rn(xc, __fmul_rn(w, 0.5f)), 0.0f);
    float y1 = fmaxf(__fsub_rn(yc, __fmul_rn(h, 0.5f)), 0.0f);
    float x2 = fminf(__fadd_rn(xc, __fmul_rn(w, 0.5f)), IMGF);
    float y2 = fminf(__fadd_rn(yc, __fmul_rn(h, 0.5f)), IMGF);

    int pos = atomicAdd(&ws->count, 1);
    if (pos < CAP) {
        ws->score[pos] = sig;
        ws->anchor[pos] = a;
        ws->label[pos] = lbl;
        ws->box[pos] = make_float4(x1, y1, x2, y2);
    }
}

// Phase 2: ONE wave, no sort, no barriers in the pick loop.
// Pick = max over active of key (score_bits<<32 | ~anchor)  == reference's
// "first active in argsort(-scores) order". Suppression: each lane owns 64
// candidates as a register bitmask and clears its own bits (self-IoU==1 removes
// the pick; degenerate zero-area boxes behave exactly like the reference).
__global__ __launch_bounds__(64, 1) void nms_kernel(const Ws* __restrict__ ws,
                                                    float* __restrict__ out) {
    __shared__ unsigned long long skey[CAP];
    __shared__ float4 sbox[CAP];

    int lane = threadIdx.x;
    int n = ws->count;
    if (n > CAP) n = CAP;

    for (int s = lane; s < n; s += 64) {
        int p = swz(s);
        unsigned int sb = __float_as_uint(ws->score[s]);
        skey[p] = ((unsigned long long)sb << 32) |
                  (unsigned int)(0xFFFFFFFFu - (unsigned int)ws->anchor[s]);
        sbox[p] = ws->box[s];
    }
    __syncthreads();  // single wave: cheap; orders LDS writes before cross-lane reads

    unsigned long long mybits;
    {
        int rem = n - (lane << 6);
        mybits = (rem >= 64) ? ~0ull : ((rem > 0) ? ((1ull << rem) - 1ull) : 0ull);
    }

    int k0 = 0, k1 = 0;  // keep slots: pick #lane and pick #(64+lane)
    int nk = 0;
    int base = lane << 6;

    for (int it = 0; it < MAX_DETS; ++it) {
        // per-lane local argmax over still-active owned candidates
        unsigned long long bk = 0ull;
        int bs = 0;
        unsigned long long t = mybits;
        while (t) {
            int b = __builtin_ctzll(t);
            t &= t - 1;
            int p = base | ((b + lane) & 63);
            unsigned long long k = skey[p];
            if (k > bk) { bk = k; bs = base + b; }
        }
        // wave reduce (key, slot)
#pragma unroll
        for (int d = 1; d < 64; d <<= 1) {
            unsigned long long ok = __shfl_xor(bk, d, 64);
            int os = __shfl_xor(bs, d, 64);
            if (ok > bk) { bk = ok; bs = os; }
        }
        if (bk == 0ull) break;  // nothing active

        if (it < 64) { if (lane == it) k0 = bs; }
        else         { if (lane == it - 64) k1 = bs; }
        ++nk;

        float4 pb = sbox[swz(bs)];  // uniform address -> broadcast
        float pa = __fmul_rn(__fsub_rn(pb.z, pb.x), __fsub_rn(pb.w, pb.y));

        // suppress among my owned active candidates
        t = mybits;
        while (t) {
            int b = __builtin_ctzll(t);
            t &= t - 1;
            int p = base | ((b + lane) & 63);
            float4 cb = sbox[p];
            float ca = __fmul_rn(__fsub_rn(cb.z, cb.x), __fsub_rn(cb.w, cb.y));
            float ix1 = fmaxf(pb.x, cb.x);
            float iy1 = fmaxf(pb.y, cb.y);
            float ix2 = fminf(pb.z, cb.z);
            float iy2 = fminf(pb.w, cb.w);
            float iw = fmaxf(__fsub_rn(ix2, ix1), 0.0f);
            float ih = fmaxf(__fsub_rn(iy2, iy1), 0.0f);
            float inter = __fmul_rn(iw, ih);
            float denom = __fadd_rn(__fadd_rn(__fadd_rn(pa, ca), -inter), 1e-8f);
            float iou = __fdiv_rn(inter, denom);
            if (!(iou < IOU_T)) mybits &= ~(1ull << b);
        }
    }

    // write 100 boxes + 100 scores + 100 labels (zeros for invalid)
    for (int o = lane; o < MAX_DETS; o += 64) {
        float b0 = 0.f, b1 = 0.f, b2 = 0.f, b3 = 0.f, sc = 0.f, lb = 0.f;
        int ks = (o < 64) ? k0 : k1;
        if (o < nk) {
            float4 bb = sbox[swz(ks)];
            unsigned long long kk = skey[swz(ks)];
            b0 = bb.x; b1 = bb.y; b2 = bb.z; b3 = bb.w;
            sc = __uint_as_float((unsigned int)(kk >> 32));
            lb = (float)ws->label[ks];
        }
        out[o * 4 + 0] = b0;
        out[o * 4 + 1] = b1;
        out[o * 4 + 2] = b2;
        out[o * 4 + 3] = b3;
        out[400 + o] = sc;
        out[500 + o] = lb;
    }
}

extern "C" void kernel_launch(void* const* d_in, const int* in_sizes, int n_in,
                              void* d_out, int out_size, void* d_ws, size_t ws_size,
                              hipStream_t stream) {
    const float* reg = (const float*)d_in[1];
    const float* cls = (const float*)d_in[2];
    const float* anc = (const float*)d_in[3];
    Ws* ws = (Ws*)d_ws;

    hipMemsetAsync(d_ws, 0, sizeof(int), stream);  // zero candidate count

    int blocks = (A_TOTAL * 4 + 255) / 256;
    score_decode_kernel<<<blocks, 256, 0, stream>>>(cls, reg, anc, ws);
    nms_kernel<<<1, 64, 0, stream>>>(ws, (float*)d_out);
}

// Round 6
// 315.269 us; speedup vs baseline: 4.4235x; 4.4235x over previous
//
#include <hip/hip_runtime.h>
#include <hip/hip_bf16.h>

#define A_TOTAL 110484
#define NCLS 80
#define CAP 2048          // storage cap; n ~ 1330 expected (mean + ~20 sigma)
#define NW 26             // sweep words: 26*64 = 1664 candidates considered
#define SWEEP_CAP (NW * 64)
#define MAX_DETS 100
#define IMGF 768.0f
#define IOU_T 0.2f

struct Ws {
    int count;
    int pad[3];
    unsigned long long key[CAP];   // unsorted: score_bits<<32 | ~anchor
    float4 box[CAP];               // unsorted decoded boxes
    int label[CAP];
    unsigned long long skey[CAP];  // sorted (descending key == argsort(-scores))
    float4 sbox[CAP];
    int slabel[CAP];
};

// Phase 1: per-anchor max/argmax over 80 classes, sigmoid+threshold, decode+clip,
// atomic compaction. Numerics identical to round-3 (validated absmax 0.0).
__global__ void score_decode_kernel(const float* __restrict__ cls,
                                    const float* __restrict__ reg,
                                    const float* __restrict__ anc,
                                    Ws* __restrict__ ws) {
    int a = blockIdx.x * blockDim.x + threadIdx.x;
    if (a >= A_TOTAL) return;

    const float4* row = (const float4*)(cls + (size_t)a * NCLS);
    float m = -1e30f;
    int lbl = 0;
#pragma unroll
    for (int i = 0; i < NCLS / 4; ++i) {
        float4 v = row[i];
        if (v.x > m) { m = v.x; lbl = i * 4 + 0; }
        if (v.y > m) { m = v.y; lbl = i * 4 + 1; }
        if (v.z > m) { m = v.z; lbl = i * 4 + 2; }
        if (v.w > m) { m = v.w; lbl = i * 4 + 3; }
    }

    float sig = 1.0f / (1.0f + expf(-m));
    if (!(sig > 0.2f)) return;

    float4 ab = ((const float4*)anc)[a];  // y1,x1,y2,x2
    float4 rb = ((const float4*)reg)[a];  // dy,dx,dh,dw
    float ya = __fmul_rn(__fadd_rn(ab.x, ab.z), 0.5f);
    float xa = __fmul_rn(__fadd_rn(ab.y, ab.w), 0.5f);
    float ha = __fsub_rn(ab.z, ab.x);
    float wa = __fsub_rn(ab.w, ab.y);
    float w = __fmul_rn(expf(rb.w), wa);
    float h = __fmul_rn(expf(rb.z), ha);
    float yc = __fadd_rn(__fmul_rn(rb.x, ha), ya);
    float xc = __fadd_rn(__fmul_rn(rb.y, wa), xa);
    float x1 = fmaxf(__fsub_rn(xc, __fmul_rn(w, 0.5f)), 0.0f);
    float y1 = fmaxf(__fsub_rn(yc, __fmul_rn(h, 0.5f)), 0.0f);
    float x2 = fminf(__fadd_rn(xc, __fmul_rn(w, 0.5f)), IMGF);
    float y2 = fminf(__fadd_rn(yc, __fmul_rn(h, 0.5f)), IMGF);

    int pos = atomicAdd(&ws->count, 1);
    if (pos < CAP) {
        ws->key[pos] = ((unsigned long long)__float_as_uint(sig) << 32) |
                       (unsigned int)(0xFFFFFFFFu - (unsigned int)a);
        ws->box[pos] = make_float4(x1, y1, x2, y2);
        ws->label[pos] = lbl;
    }
}

// Phase 2a: multi-block rank sort. rank_i = #{j: key_j > key_i} (keys unique ->
// permutation). Uniform broadcast reads, L1/L2-resident (~11 KB of keys).
__global__ __launch_bounds__(256) void rank_kernel(Ws* __restrict__ ws) {
    int i = blockIdx.x * 256 + threadIdx.x;
    int n = ws->count;
    if (n > CAP) n = CAP;
    if (i >= n) return;

    unsigned long long my = ws->key[i];
    int r = 0;
#pragma unroll 4
    for (int j = 0; j < n; ++j) r += (ws->key[j] > my) ? 1 : 0;

    ws->skey[r] = my;
    ws->sbox[r] = ws->box[i];
    ws->slabel[r] = ws->label[i];
}

// Phase 2b: single-wave sweep over sorted candidates.
// Boxes live in per-lane REGISTERS (static unroll -> no scratch); active bits:
// lane w owns suppression word w. Next keep = next set bit after pointer
// (ballot+ctz+shfl). Suppression: IoU -> ballot -> owner-lane AND, dead words
// skipped via uniform scalar branch.
__global__ __launch_bounds__(64, 1) void sweep_kernel(const Ws* __restrict__ ws,
                                                      float* __restrict__ out) {
    __shared__ float4 sbox_lds[SWEEP_CAP];
    int lane = threadIdx.x;
    int n = ws->count;
    if (n > CAP) n = CAP;
    if (n > SWEEP_CAP) n = SWEEP_CAP;

    float4 B[NW];
    float AR[NW];
#pragma unroll
    for (int w = 0; w < NW; ++w) {
        int idx = (w << 6) | lane;
        float4 v = make_float4(0.f, 0.f, 0.f, 0.f);
        if (idx < n) v = ws->sbox[idx];
        B[w] = v;
        AR[w] = __fmul_rn(__fsub_rn(v.z, v.x), __fsub_rn(v.w, v.y));
        sbox_lds[idx] = v;
    }

    unsigned long long act;
    {
        int rem = n - (lane << 6);
        act = (rem >= 64) ? ~0ull : ((rem > 0) ? ((1ull << rem) - 1ull) : 0ull);
    }

    int k0 = 0, k1 = 0, nk = 0, cur = -1;

    for (int it = 0; it < MAX_DETS; ++it) {
        // find next active sorted index > cur
        unsigned long long eff = act;
        int curw = cur >> 6;
        if (lane == curw) eff &= ~((2ull << (cur & 63)) - 1ull);
        if (lane < curw) eff = 0ull;
        unsigned long long nz = __ballot(eff != 0ull);
        if (nz == 0ull) break;
        int w = __builtin_ctzll(nz);
        unsigned long long word = __shfl(eff, w, 64);
        int pick = (w << 6) | __builtin_ctzll(word);
        cur = pick;
        if (it < 64) { if (lane == it) k0 = pick; }
        else         { if (lane == it - 64) k1 = pick; }
        ++nk;

        float4 kb = sbox_lds[pick];  // uniform address -> LDS broadcast
        float ka = __fmul_rn(__fsub_rn(kb.z, kb.x), __fsub_rn(kb.w, kb.y));

        unsigned long long nzw = __ballot(act != 0ull);  // skip dead words (uniform)
#pragma unroll
        for (int ww = 0; ww < NW; ++ww) {
            if ((nzw >> ww) & 1ull) {
                float4 cb = B[ww];
                float ix1 = fmaxf(kb.x, cb.x);
                float iy1 = fmaxf(kb.y, cb.y);
                float ix2 = fminf(kb.z, cb.z);
                float iy2 = fminf(kb.w, cb.w);
                float iw = fmaxf(__fsub_rn(ix2, ix1), 0.0f);
                float ih = fmaxf(__fsub_rn(iy2, iy1), 0.0f);
                float inter = __fmul_rn(iw, ih);
                float denom = __fadd_rn(__fadd_rn(__fadd_rn(ka, AR[ww]), -inter), 1e-8f);
                float iou = __fdiv_rn(inter, denom);
                unsigned long long bal = __ballot(!(iou < IOU_T));
                if (lane == ww) act &= ~bal;
            }
        }
    }

    // outputs: 100 boxes + 100 scores + 100 labels (zeros for invalid slots)
    for (int o = lane; o < MAX_DETS; o += 64) {
        float b0 = 0.f, b1 = 0.f, b2 = 0.f, b3 = 0.f, sc = 0.f, lb = 0.f;
        int pick = (o < 64) ? k0 : k1;
        if (o < nk) {
            float4 bb = sbox_lds[pick];
            b0 = bb.x; b1 = bb.y; b2 = bb.z; b3 = bb.w;
            sc = __uint_as_float((unsigned int)(ws->skey[pick] >> 32));
            lb = (float)ws->slabel[pick];
        }
        out[o * 4 + 0] = b0;
        out[o * 4 + 1] = b1;
        out[o * 4 + 2] = b2;
        out[o * 4 + 3] = b3;
        out[400 + o] = sc;
        out[500 + o] = lb;
    }
}

extern "C" void kernel_launch(void* const* d_in, const int* in_sizes, int n_in,
                              void* d_out, int out_size, void* d_ws, size_t ws_size,
                              hipStream_t stream) {
    const float* reg = (const float*)d_in[1];
    const float* cls = (const float*)d_in[2];
    const float* anc = (const float*)d_in[3];
    Ws* ws = (Ws*)d_ws;

    hipMemsetAsync(d_ws, 0, sizeof(int), stream);  // zero candidate count

    int blocks = (A_TOTAL + 255) / 256;
    score_decode_kernel<<<blocks, 256, 0, stream>>>(cls, reg, anc, ws);
    rank_kernel<<<CAP / 256, 256, 0, stream>>>(ws);
    sweep_kernel<<<1, 64, 0, stream>>>(ws, (float*)d_out);
}

// Round 8
// 199.649 us; speedup vs baseline: 6.9852x; 1.5791x over previous
//
#include <hip/hip_runtime.h>
#include <hip/hip_bf16.h>

#define A_TOTAL 110484
#define NCLS 80
#define CAP 2048          // storage cap; n ~ 1330 expected
#define NW 26             // suppression words per row: 26*64 = 1664
#define SWEEP_CAP (NW * 64)
#define MAX_DETS 100
#define IMGF 768.0f
#define IOU_T 0.2f
#define CHUNK 32

struct Ws {
    int count;
    int pad[3];
    unsigned long long key[CAP];   // unsorted: score_bits<<32 | ~anchor
    float4 box[CAP];
    int label[CAP];
    unsigned long long skey[CAP];  // sorted descending == argsort(-scores)
    float4 sbox[CAP];
    int slabel[CAP];
    unsigned long long M[SWEEP_CAP * NW];  // suppression bit-matrix (row-major)
};

// Phase 1: per-anchor max/argmax, sigmoid+threshold, decode+clip, compaction.
// Numerics identical to the version that validated absmax 0.0.
__global__ void score_decode_kernel(const float* __restrict__ cls,
                                    const float* __restrict__ reg,
                                    const float* __restrict__ anc,
                                    Ws* __restrict__ ws) {
    int a = blockIdx.x * blockDim.x + threadIdx.x;
    if (a >= A_TOTAL) return;

    const float4* row = (const float4*)(cls + (size_t)a * NCLS);
    float m = -1e30f;
    int lbl = 0;
#pragma unroll
    for (int i = 0; i < NCLS / 4; ++i) {
        float4 v = row[i];
        if (v.x > m) { m = v.x; lbl = i * 4 + 0; }
        if (v.y > m) { m = v.y; lbl = i * 4 + 1; }
        if (v.z > m) { m = v.z; lbl = i * 4 + 2; }
        if (v.w > m) { m = v.w; lbl = i * 4 + 3; }
    }

    float sig = 1.0f / (1.0f + expf(-m));
    if (!(sig > 0.2f)) return;

    float4 ab = ((const float4*)anc)[a];
    float4 rb = ((const float4*)reg)[a];
    float ya = __fmul_rn(__fadd_rn(ab.x, ab.z), 0.5f);
    float xa = __fmul_rn(__fadd_rn(ab.y, ab.w), 0.5f);
    float ha = __fsub_rn(ab.z, ab.x);
    float wa = __fsub_rn(ab.w, ab.y);
    float w = __fmul_rn(expf(rb.w), wa);
    float h = __fmul_rn(expf(rb.z), ha);
    float yc = __fadd_rn(__fmul_rn(rb.x, ha), ya);
    float xc = __fadd_rn(__fmul_rn(rb.y, wa), xa);
    float x1 = fmaxf(__fsub_rn(xc, __fmul_rn(w, 0.5f)), 0.0f);
    float y1 = fmaxf(__fsub_rn(yc, __fmul_rn(h, 0.5f)), 0.0f);
    float x2 = fminf(__fadd_rn(xc, __fmul_rn(w, 0.5f)), IMGF);
    float y2 = fminf(__fadd_rn(yc, __fmul_rn(h, 0.5f)), IMGF);

    int pos = atomicAdd(&ws->count, 1);
    if (pos < CAP) {
        ws->key[pos] = ((unsigned long long)__float_as_uint(sig) << 32) |
                       (unsigned int)(0xFFFFFFFFu - (unsigned int)a);
        ws->box[pos] = make_float4(x1, y1, x2, y2);
        ws->label[pos] = lbl;
    }
}

// Phase 2a: multi-block rank sort (keys unique -> permutation).
__global__ __launch_bounds__(256) void rank_kernel(Ws* __restrict__ ws) {
    int i = blockIdx.x * 256 + threadIdx.x;
    int n = ws->count;
    if (n > CAP) n = CAP;
    if (i >= n) return;

    unsigned long long my = ws->key[i];
    int r = 0;
#pragma unroll 4
    for (int j = 0; j < n; ++j) r += (ws->key[j] > my) ? 1 : 0;

    ws->skey[r] = my;
    ws->sbox[r] = ws->box[i];
    ws->slabel[r] = ws->label[i];
}

// Phase 2b: suppression bit-matrix. One wave per (row i, word w): lane b
// computes iou(box_i, box_{w*64+b}); ballot -> M[i*NW+w]. Rows/cols beyond n
// are garbage-but-harmless (act bits there are always 0; AND only clears).
__global__ __launch_bounds__(256) void mask_kernel(Ws* __restrict__ ws) {
    int gw = (blockIdx.x * 256 + threadIdx.x) >> 6;
    int lane = threadIdx.x & 63;
    if (gw >= SWEEP_CAP * NW) return;
    int i = gw / NW;
    int w = gw - i * NW;
    int n = ws->count;
    if (n > CAP) n = CAP;
    if (n > SWEEP_CAP) n = SWEEP_CAP;
    if (i >= n) {
        if (lane == 0) ws->M[gw] = 0ull;
        return;
    }

    float4 kb = ws->sbox[i];  // uniform -> broadcast
    float ka = __fmul_rn(__fsub_rn(kb.z, kb.x), __fsub_rn(kb.w, kb.y));
    int j = (w << 6) | lane;
    float4 cb = ws->sbox[j];  // coalesced
    float ca = __fmul_rn(__fsub_rn(cb.z, cb.x), __fsub_rn(cb.w, cb.y));
    float ix1 = fmaxf(kb.x, cb.x);
    float iy1 = fmaxf(kb.y, cb.y);
    float ix2 = fminf(kb.z, cb.z);
    float iy2 = fminf(kb.w, cb.w);
    float iw = fmaxf(__fsub_rn(ix2, ix1), 0.0f);
    float ih = fmaxf(__fsub_rn(iy2, iy1), 0.0f);
    float inter = __fmul_rn(iw, ih);
    float denom = __fadd_rn(__fadd_rn(__fadd_rn(ka, ca), -inter), 1e-8f);
    float iou = __fdiv_rn(inter, denom);
    unsigned long long bal = __ballot(!(iou < IOU_T));
    if (lane == 0) ws->M[gw] = bal;
}

// Phase 2c: linear sweep. Bit i active when reached => keep i; act &= ~M[i].
// M rows prefetched in chunks (address-independent loads pipeline under vmcnt).
// Per index: 1 shfl + bit test (uniform). Early-exit at MAX_DETS keeps.
__global__ __launch_bounds__(64, 1) void sweep_kernel(const Ws* __restrict__ ws,
                                                      float* __restrict__ out) {
    int lane = threadIdx.x;
    int n = ws->count;
    if (n > CAP) n = CAP;
    if (n > SWEEP_CAP) n = SWEEP_CAP;

    unsigned long long act;
    {
        int rem = n - (lane << 6);
        act = (rem >= 64) ? ~0ull : ((rem > 0) ? ((1ull << rem) - 1ull) : 0ull);
        if (lane >= NW) act = 0ull;
    }

    int k0 = 0, k1 = 0, nk = 0;

    for (int c = 0; c < SWEEP_CAP; c += CHUNK) {
        if (c >= n || nk >= MAX_DETS) break;
        unsigned long long r[CHUNK];
#pragma unroll
        for (int t = 0; t < CHUNK; ++t)
            r[t] = (lane < NW) ? ws->M[(size_t)(c + t) * NW + lane] : 0ull;
#pragma unroll
        for (int t = 0; t < CHUNK; ++t) {
            int i = c + t;
            unsigned long long aw = __shfl(act, i >> 6, 64);
            if (((aw >> (i & 63)) & 1ull) && i < n && nk < MAX_DETS) {
                if (nk < 64) { if (lane == nk) k0 = i; }
                else         { if (lane == nk - 64) k1 = i; }
                ++nk;
                act &= ~r[t];
            }
        }
    }

    // outputs: 100 boxes + 100 scores + 100 labels (zeros for invalid slots)
    for (int o = lane; o < MAX_DETS; o += 64) {
        float b0 = 0.f, b1 = 0.f, b2 = 0.f, b3 = 0.f, sc = 0.f, lb = 0.f;
        int pick = (o < 64) ? k0 : k1;
        if (o < nk) {
            float4 bb = ws->sbox[pick];
            b0 = bb.x; b1 = bb.y; b2 = bb.z; b3 = bb.w;
            sc = __uint_as_float((unsigned int)(ws->skey[pick] >> 32));
            lb = (float)ws->slabel[pick];
        }
        out[o * 4 + 0] = b0;
        out[o * 4 + 1] = b1;
        out[o * 4 + 2] = b2;
        out[o * 4 + 3] = b3;
        out[400 + o] = sc;
        out[500 + o] = lb;
    }
}

extern "C" void kernel_launch(void* const* d_in, const int* in_sizes, int n_in,
                              void* d_out, int out_size, void* d_ws, size_t ws_size,
                              hipStream_t stream) {
    const float* reg = (const float*)d_in[1];
    const float* cls = (const float*)d_in[2];
    const float* anc = (const float*)d_in[3];
    Ws* ws = (Ws*)d_ws;

    hipMemsetAsync(d_ws, 0, sizeof(int), stream);  // zero candidate count

    int blocks = (A_TOTAL + 255) / 256;
    score_decode_kernel<<<blocks, 256, 0, stream>>>(cls, reg, anc, ws);
    rank_kernel<<<CAP / 256, 256, 0, stream>>>(ws);
    mask_kernel<<<(SWEEP_CAP * NW + 3) / 4, 256, 0, stream>>>(ws);
    sweep_kernel<<<1, 64, 0, stream>>>(ws, (float*)d_out);
}

// Round 10
// 168.324 us; speedup vs baseline: 8.2852x; 1.1861x over previous
//
#include <hip/hip_runtime.h>
#include <hip/hip_bf16.h>

#define A_TOTAL 110484
#define NCLS 80
#define CAP 2048          // storage cap; n ~ 1330 expected
#define NW 26             // suppression words per row: 26*64 = 1664
#define SWEEP_CAP (NW * 64)
#define MAX_DETS 100
#define IMGF 768.0f
#define IOU_T 0.2f
#define CHUNK 32

struct Ws {
    int count;
    int pad[3];
    unsigned long long key[CAP];   // unsorted: score_bits<<32 | ~anchor
    float4 box[CAP];
    int label[CAP];
    unsigned long long skey[CAP];  // sorted descending == argsort(-scores)
    float4 sbox[CAP];
    int slabel[CAP];
    unsigned long long M[SWEEP_CAP * NW];  // suppression bit-matrix (row-major)
};

// Phase 1: per-anchor max/argmax, sigmoid+threshold, decode+clip, compaction.
// Numerics identical to the version that validated absmax 0.0.
__global__ void score_decode_kernel(const float* __restrict__ cls,
                                    const float* __restrict__ reg,
                                    const float* __restrict__ anc,
                                    Ws* __restrict__ ws) {
    int a = blockIdx.x * blockDim.x + threadIdx.x;
    if (a >= A_TOTAL) return;

    const float4* row = (const float4*)(cls + (size_t)a * NCLS);
    float m = -1e30f;
    int lbl = 0;
#pragma unroll
    for (int i = 0; i < NCLS / 4; ++i) {
        float4 v = row[i];
        if (v.x > m) { m = v.x; lbl = i * 4 + 0; }
        if (v.y > m) { m = v.y; lbl = i * 4 + 1; }
        if (v.z > m) { m = v.z; lbl = i * 4 + 2; }
        if (v.w > m) { m = v.w; lbl = i * 4 + 3; }
    }

    float sig = 1.0f / (1.0f + expf(-m));
    if (!(sig > 0.2f)) return;

    float4 ab = ((const float4*)anc)[a];
    float4 rb = ((const float4*)reg)[a];
    float ya = __fmul_rn(__fadd_rn(ab.x, ab.z), 0.5f);
    float xa = __fmul_rn(__fadd_rn(ab.y, ab.w), 0.5f);
    float ha = __fsub_rn(ab.z, ab.x);
    float wa = __fsub_rn(ab.w, ab.y);
    float w = __fmul_rn(expf(rb.w), wa);
    float h = __fmul_rn(expf(rb.z), ha);
    float yc = __fadd_rn(__fmul_rn(rb.x, ha), ya);
    float xc = __fadd_rn(__fmul_rn(rb.y, wa), xa);
    float x1 = fmaxf(__fsub_rn(xc, __fmul_rn(w, 0.5f)), 0.0f);
    float y1 = fmaxf(__fsub_rn(yc, __fmul_rn(h, 0.5f)), 0.0f);
    float x2 = fminf(__fadd_rn(xc, __fmul_rn(w, 0.5f)), IMGF);
    float y2 = fminf(__fadd_rn(yc, __fmul_rn(h, 0.5f)), IMGF);

    int pos = atomicAdd(&ws->count, 1);
    if (pos < CAP) {
        ws->key[pos] = ((unsigned long long)__float_as_uint(sig) << 32) |
                       (unsigned int)(0xFFFFFFFFu - (unsigned int)a);
        ws->box[pos] = make_float4(x1, y1, x2, y2);
        ws->label[pos] = lbl;
    }
}

// Phase 2a: rank sort with LDS-staged keys. Each block stages all n keys into
// LDS (coalesced), then each thread's rank loop reads wave-uniform LDS
// (broadcast, ~6 cyc/iter issue) instead of latency-bound global loads.
__global__ __launch_bounds__(256) void rank_kernel(Ws* __restrict__ ws) {
    __shared__ unsigned long long kl[CAP];
    int tid = threadIdx.x;
    int n = ws->count;
    if (n > CAP) n = CAP;

    for (int j = tid; j < n; j += 256) kl[j] = ws->key[j];
    __syncthreads();

    int i = blockIdx.x * 256 + tid;
    if (i >= n) return;

    unsigned long long my = kl[i];
    int r = 0;
    int j = 0;
    for (; j + 8 <= n; j += 8) {
        r += (kl[j + 0] > my) ? 1 : 0;
        r += (kl[j + 1] > my) ? 1 : 0;
        r += (kl[j + 2] > my) ? 1 : 0;
        r += (kl[j + 3] > my) ? 1 : 0;
        r += (kl[j + 4] > my) ? 1 : 0;
        r += (kl[j + 5] > my) ? 1 : 0;
        r += (kl[j + 6] > my) ? 1 : 0;
        r += (kl[j + 7] > my) ? 1 : 0;
    }
    for (; j < n; ++j) r += (kl[j] > my) ? 1 : 0;

    ws->skey[r] = my;
    ws->sbox[r] = ws->box[i];
    ws->slabel[r] = ws->label[i];
}

// Phase 2b: suppression bit-matrix. One wave per (row i, word w): lane b
// computes iou(box_i, box_{w*64+b}); ballot -> M[i*NW+w]. Rows/cols beyond n
// are garbage-but-harmless (act bits there are always 0; AND only clears).
__global__ __launch_bounds__(256) void mask_kernel(Ws* __restrict__ ws) {
    int gw = (blockIdx.x * 256 + threadIdx.x) >> 6;
    int lane = threadIdx.x & 63;
    if (gw >= SWEEP_CAP * NW) return;
    int i = gw / NW;
    int w = gw - i * NW;
    int n = ws->count;
    if (n > CAP) n = CAP;
    if (n > SWEEP_CAP) n = SWEEP_CAP;
    if (i >= n) {
        if (lane == 0) ws->M[gw] = 0ull;
        return;
    }

    float4 kb = ws->sbox[i];  // uniform -> broadcast
    float ka = __fmul_rn(__fsub_rn(kb.z, kb.x), __fsub_rn(kb.w, kb.y));
    int j = (w << 6) | lane;
    float4 cb = ws->sbox[j];  // coalesced
    float ca = __fmul_rn(__fsub_rn(cb.z, cb.x), __fsub_rn(cb.w, cb.y));
    float ix1 = fmaxf(kb.x, cb.x);
    float iy1 = fmaxf(kb.y, cb.y);
    float ix2 = fminf(kb.z, cb.z);
    float iy2 = fminf(kb.w, cb.w);
    float iw = fmaxf(__fsub_rn(ix2, ix1), 0.0f);
    float ih = fmaxf(__fsub_rn(iy2, iy1), 0.0f);
    float inter = __fmul_rn(iw, ih);
    float denom = __fadd_rn(__fadd_rn(__fadd_rn(ka, ca), -inter), 1e-8f);
    float iou = __fdiv_rn(inter, denom);
    unsigned long long bal = __ballot(!(iou < IOU_T));
    if (lane == 0) ws->M[gw] = bal;
}

// Phase 2c: linear sweep. Bit i active when reached => keep i; act &= ~M[i].
// M rows prefetched in chunks (address-independent loads pipeline under vmcnt).
// Per index: 1 shfl + bit test (uniform). Early-exit at MAX_DETS keeps.
__global__ __launch_bounds__(64, 1) void sweep_kernel(const Ws* __restrict__ ws,
                                                      float* __restrict__ out) {
    int lane = threadIdx.x;
    int n = ws->count;
    if (n > CAP) n = CAP;
    if (n > SWEEP_CAP) n = SWEEP_CAP;

    unsigned long long act;
    {
        int rem = n - (lane << 6);
        act = (rem >= 64) ? ~0ull : ((rem > 0) ? ((1ull << rem) - 1ull) : 0ull);
        if (lane >= NW) act = 0ull;
    }

    int k0 = 0, k1 = 0, nk = 0;

    for (int c = 0; c < SWEEP_CAP; c += CHUNK) {
        if (c >= n || nk >= MAX_DETS) break;
        unsigned long long r[CHUNK];
#pragma unroll
        for (int t = 0; t < CHUNK; ++t)
            r[t] = (lane < NW) ? ws->M[(size_t)(c + t) * NW + lane] : 0ull;
#pragma unroll
        for (int t = 0; t < CHUNK; ++t) {
            int i = c + t;
            unsigned long long aw = __shfl(act, i >> 6, 64);
            if (((aw >> (i & 63)) & 1ull) && i < n && nk < MAX_DETS) {
                if (nk < 64) { if (lane == nk) k0 = i; }
                else         { if (lane == nk - 64) k1 = i; }
                ++nk;
                act &= ~r[t];
            }
        }
    }

    // outputs: 100 boxes + 100 scores + 100 labels (zeros for invalid slots)
    for (int o = lane; o < MAX_DETS; o += 64) {
        float b0 = 0.f, b1 = 0.f, b2 = 0.f, b3 = 0.f, sc = 0.f, lb = 0.f;
        int pick = (o < 64) ? k0 : k1;
        if (o < nk) {
            float4 bb = ws->sbox[pick];
            b0 = bb.x; b1 = bb.y; b2 = bb.z; b3 = bb.w;
            sc = __uint_as_float((unsigned int)(ws->skey[pick] >> 32));
            lb = (float)ws->slabel[pick];
        }
        out[o * 4 + 0] = b0;
        out[o * 4 + 1] = b1;
        out[o * 4 + 2] = b2;
        out[o * 4 + 3] = b3;
        out[400 + o] = sc;
        out[500 + o] = lb;
    }
}

extern "C" void kernel_launch(void* const* d_in, const int* in_sizes, int n_in,
                              void* d_out, int out_size, void* d_ws, size_t ws_size,
                              hipStream_t stream) {
    const float* reg = (const float*)d_in[1];
    const float* cls = (const float*)d_in[2];
    const float* anc = (const float*)d_in[3];
    Ws* ws = (Ws*)d_ws;

    hipMemsetAsync(d_ws, 0, sizeof(int), stream);  // zero candidate count

    int blocks = (A_TOTAL + 255) / 256;
    score_decode_kernel<<<blocks, 256, 0, stream>>>(cls, reg, anc, ws);
    rank_kernel<<<CAP / 256, 256, 0, stream>>>(ws);
    mask_kernel<<<(SWEEP_CAP * NW + 3) / 4, 256, 0, stream>>>(ws);
    sweep_kernel<<<1, 64, 0, stream>>>(ws, (float*)d_out);
}

// Round 13
// 159.728 us; speedup vs baseline: 8.7311x; 1.0538x over previous
//
#include <hip/hip_runtime.h>
#include <hip/hip_bf16.h>

#define A_TOTAL 110484
#define NCLS 80
#define CAP 2048          // storage cap; n ~ 1330 expected
#define NW 26             // suppression words per row: 26*64 = 1664
#define SWEEP_CAP (NW * 64)
#define MAX_DETS 100
#define IMGF 768.0f
#define IOU_T 0.2f

struct Ws {
    int count;
    int pad[3];
    unsigned long long key[CAP];   // unsorted: score_bits<<32 | ~anchor
    float4 box[CAP];
    int label[CAP];
    unsigned long long skey[CAP];  // sorted descending == argsort(-scores)
    float4 sbox[CAP];
    int slabel[CAP];
    unsigned long long M[SWEEP_CAP * NW];  // suppression bit-matrix (row-major)
};

// Phase 1: 4 lanes per anchor (lanes 16B apart -> fully-used contiguous cache
// lines). Cross-lane max via monotone-float key with label tie-break
// (== jnp.argmax). Validated absmax 0.0 in round 4.
__global__ void score_decode_kernel(const float* __restrict__ cls,
                                    const float* __restrict__ reg,
                                    const float* __restrict__ anc,
                                    Ws* __restrict__ ws) {
    int gid = blockIdx.x * blockDim.x + threadIdx.x;
    int a = gid >> 2;
    int sub = gid & 3;
    if (a >= A_TOTAL) return;

    const float4* row = (const float4*)(cls + (size_t)a * NCLS);
    float m = -1e30f;
    int lbl = 0;
#pragma unroll
    for (int q = 0; q < 5; ++q) {
        float4 v = row[sub + q * 4];
        int c0 = (sub + q * 4) * 4;
        if (v.x > m) { m = v.x; lbl = c0 + 0; }
        if (v.y > m) { m = v.y; lbl = c0 + 1; }
        if (v.z > m) { m = v.z; lbl = c0 + 2; }
        if (v.w > m) { m = v.w; lbl = c0 + 3; }
    }

    // monotone mapping of float bits, tie -> min label (exact argmax semantics)
    unsigned int mb = __float_as_uint(m);
    mb ^= (mb & 0x80000000u) ? 0xFFFFFFFFu : 0x80000000u;
    unsigned long long key =
        ((unsigned long long)mb << 32) | (unsigned int)(0xFFFFFFFFu - (unsigned int)lbl);
#pragma unroll
    for (int d = 1; d < 4; d <<= 1) {
        unsigned long long o = __shfl_xor(key, d, 64);
        if (o > key) key = o;
    }
    if (sub != 0) return;

    unsigned int hb = (unsigned int)(key >> 32);
    hb ^= (hb & 0x80000000u) ? 0x80000000u : 0xFFFFFFFFu;  // inverse map
    m = __uint_as_float(hb);
    lbl = (int)(0xFFFFFFFFu - (unsigned int)(key & 0xFFFFFFFFu));

    float sig = 1.0f / (1.0f + expf(-m));
    if (!(sig > 0.2f)) return;

    float4 ab = ((const float4*)anc)[a];
    float4 rb = ((const float4*)reg)[a];
    float ya = __fmul_rn(__fadd_rn(ab.x, ab.z), 0.5f);
    float xa = __fmul_rn(__fadd_rn(ab.y, ab.w), 0.5f);
    float ha = __fsub_rn(ab.z, ab.x);
    float wa = __fsub_rn(ab.w, ab.y);
    float w = __fmul_rn(expf(rb.w), wa);
    float h = __fmul_rn(expf(rb.z), ha);
    float yc = __fadd_rn(__fmul_rn(rb.x, ha), ya);
    float xc = __fadd_rn(__fmul_rn(rb.y, wa), xa);
    float x1 = fmaxf(__fsub_rn(xc, __fmul_rn(w, 0.5f)), 0.0f);
    float y1 = fmaxf(__fsub_rn(yc, __fmul_rn(h, 0.5f)), 0.0f);
    float x2 = fminf(__fadd_rn(xc, __fmul_rn(w, 0.5f)), IMGF);
    float y2 = fminf(__fadd_rn(yc, __fmul_rn(h, 0.5f)), IMGF);

    int pos = atomicAdd(&ws->count, 1);
    if (pos < CAP) {
        ws->key[pos] = ((unsigned long long)__float_as_uint(sig) << 32) |
                       (unsigned int)(0xFFFFFFFFu - (unsigned int)a);
        ws->box[pos] = make_float4(x1, y1, x2, y2);
        ws->label[pos] = lbl;
    }
}

// Phase 2a: rank sort with LDS-staged keys (wave-uniform broadcast reads).
__global__ __launch_bounds__(256) void rank_kernel(Ws* __restrict__ ws) {
    __shared__ unsigned long long kl[CAP];
    int tid = threadIdx.x;
    int n = ws->count;
    if (n > CAP) n = CAP;

    for (int j = tid; j < n; j += 256) kl[j] = ws->key[j];
    __syncthreads();

    int i = blockIdx.x * 256 + tid;
    if (i >= n) return;

    unsigned long long my = kl[i];
    int r = 0;
    int j = 0;
    for (; j + 8 <= n; j += 8) {
        r += (kl[j + 0] > my) ? 1 : 0;
        r += (kl[j + 1] > my) ? 1 : 0;
        r += (kl[j + 2] > my) ? 1 : 0;
        r += (kl[j + 3] > my) ? 1 : 0;
        r += (kl[j + 4] > my) ? 1 : 0;
        r += (kl[j + 5] > my) ? 1 : 0;
        r += (kl[j + 6] > my) ? 1 : 0;
        r += (kl[j + 7] > my) ? 1 : 0;
    }
    for (; j < n; ++j) r += (kl[j] > my) ? 1 : 0;

    ws->skey[r] = my;
    ws->sbox[r] = ws->box[i];
    ws->slabel[r] = ws->label[i];
}

// Phase 2b: suppression bit-matrix. One wave per (row i, word w).
__global__ __launch_bounds__(256) void mask_kernel(Ws* __restrict__ ws) {
    int gw = (blockIdx.x * 256 + threadIdx.x) >> 6;
    int lane = threadIdx.x & 63;
    if (gw >= SWEEP_CAP * NW) return;
    int i = gw / NW;
    int w = gw - i * NW;
    int n = ws->count;
    if (n > CAP) n = CAP;
    if (n > SWEEP_CAP) n = SWEEP_CAP;
    if (i >= n) {
        if (lane == 0) ws->M[gw] = 0ull;
        return;
    }

    float4 kb = ws->sbox[i];  // uniform -> broadcast
    float ka = __fmul_rn(__fsub_rn(kb.z, kb.x), __fsub_rn(kb.w, kb.y));
    int j = (w << 6) | lane;
    float4 cb = ws->sbox[j];  // coalesced
    float ca = __fmul_rn(__fsub_rn(cb.z, cb.x), __fsub_rn(cb.w, cb.y));
    float ix1 = fmaxf(kb.x, cb.x);
    float iy1 = fmaxf(kb.y, cb.y);
    float ix2 = fminf(kb.z, cb.z);
    float iy2 = fminf(kb.w, cb.w);
    float iw = fmaxf(__fsub_rn(ix2, ix1), 0.0f);
    float ih = fmaxf(__fsub_rn(iy2, iy1), 0.0f);
    float inter = __fmul_rn(iw, ih);
    float denom = __fadd_rn(__fadd_rn(__fadd_rn(ka, ca), -inter), 1e-8f);
    float iou = __fdiv_rn(inter, denom);
    unsigned long long bal = __ballot(!(iou < IOU_T));
    if (lane == 0) ws->M[gw] = bal;
}

// Phase 2c: scalar-word sweep. Per word: 2 readlanes pull the active word to
// SALU; ctz walks set bits with ZERO memory ops for suppressed indices.
// Per keep only: each lane ANDs out its own M[i*NW+lane] (one 8B load), then
// 2 readlanes refresh the word. ~100 keeps x ~280 cyc dependent chain.
__global__ __launch_bounds__(64, 1) void sweep_kernel(const Ws* __restrict__ ws,
                                                      float* __restrict__ out) {
    int lane = threadIdx.x;
    int n = ws->count;
    if (n > CAP) n = CAP;
    if (n > SWEEP_CAP) n = SWEEP_CAP;

    unsigned long long act;
    {
        int rem = n - (lane << 6);
        act = (rem >= 64) ? ~0ull : ((rem > 0) ? ((1ull << rem) - 1ull) : 0ull);
        if (lane >= NW) act = 0ull;
    }

    int k0 = 0, k1 = 0, nk = 0;

    for (int w = 0; w < NW && nk < MAX_DETS; ++w) {
        unsigned int lo = __builtin_amdgcn_readlane((unsigned int)(act & 0xFFFFFFFFull), w);
        unsigned int hi = __builtin_amdgcn_readlane((unsigned int)(act >> 32), w);
        unsigned long long aw = ((unsigned long long)hi << 32) | lo;
        while (aw) {
            int b = __builtin_ctzll(aw);
            int i = (w << 6) | b;
            if (nk < 64) { if (lane == nk) k0 = i; }
            else         { if (lane == nk - 64) k1 = i; }
            ++nk;
            if (nk >= MAX_DETS) break;
            unsigned long long rowm = (lane < NW) ? ws->M[(size_t)i * NW + lane] : 0ull;
            act &= ~rowm;
            lo = __builtin_amdgcn_readlane((unsigned int)(act & 0xFFFFFFFFull), w);
            hi = __builtin_amdgcn_readlane((unsigned int)(act >> 32), w);
            aw = (((unsigned long long)hi << 32) | lo) & ~((2ull << b) - 1ull);
        }
    }

    // outputs: 100 boxes + 100 scores + 100 labels (zeros for invalid slots)
    for (int o = lane; o < MAX_DETS; o += 64) {
        float b0 = 0.f, b1 = 0.f, b2 = 0.f, b3 = 0.f, sc = 0.f, lb = 0.f;
        int pick = (o < 64) ? k0 : k1;
        if (o < nk) {
            float4 bb = ws->sbox[pick];
            b0 = bb.x; b1 = bb.y; b2 = bb.z; b3 = bb.w;
            sc = __uint_as_float((unsigned int)(ws->skey[pick] >> 32));
            lb = (float)ws->slabel[pick];
        }
        out[o * 4 + 0] = b0;
        out[o * 4 + 1] = b1;
        out[o * 4 + 2] = b2;
        out[o * 4 + 3] = b3;
        out[400 + o] = sc;
        out[500 + o] = lb;
    }
}

extern "C" void kernel_launch(void* const* d_in, const int* in_sizes, int n_in,
                              void* d_out, int out_size, void* d_ws, size_t ws_size,
                              hipStream_t stream) {
    const float* reg = (const float*)d_in[1];
    const float* cls = (const float*)d_in[2];
    const float* anc = (const float*)d_in[3];
    Ws* ws = (Ws*)d_ws;

    hipMemsetAsync(d_ws, 0, sizeof(int), stream);  // zero candidate count

    int blocks = (A_TOTAL * 4 + 255) / 256;
    score_decode_kernel<<<blocks, 256, 0, stream>>>(cls, reg, anc, ws);
    rank_kernel<<<CAP / 256, 256, 0, stream>>>(ws);
    mask_kernel<<<(SWEEP_CAP * NW + 3) / 4, 256, 0, stream>>>(ws);
    sweep_kernel<<<1, 64, 0, stream>>>(ws, (float*)d_out);
}

// Round 15
// 153.085 us; speedup vs baseline: 9.1099x; 1.0434x over previous
//
#include <hip/hip_runtime.h>
#include <hip/hip_bf16.h>

#define A_TOTAL 110484
#define NCLS 80
#define CAP 2048          // storage cap; n ~ 1330 expected
#define NW 26             // suppression words per row: 26*64 = 1664
#define SWEEP_CAP (NW * 64)
#define MAX_DETS 100
#define IMGF 768.0f
#define IOU_T 0.2f

struct Ws {
    int count;
    int pad[3];
    unsigned long long key[CAP];   // unsorted: score_bits<<32 | ~anchor
    float4 box[CAP];
    int label[CAP];
    unsigned long long skey[CAP];  // sorted descending == argsort(-scores)
    float4 sbox[CAP];
    int slabel[CAP];
    unsigned long long M[SWEEP_CAP * NW];  // suppression bit-matrix (row-major)
};

// Phase 1: 4 lanes per anchor; exact argmax tie-break; decode+clip; compaction.
// Numerics validated absmax 0.0 (rounds 4/13).
__global__ void score_decode_kernel(const float* __restrict__ cls,
                                    const float* __restrict__ reg,
                                    const float* __restrict__ anc,
                                    Ws* __restrict__ ws) {
    int gid = blockIdx.x * blockDim.x + threadIdx.x;
    int a = gid >> 2;
    int sub = gid & 3;
    if (a >= A_TOTAL) return;

    const float4* row = (const float4*)(cls + (size_t)a * NCLS);
    float m = -1e30f;
    int lbl = 0;
#pragma unroll
    for (int q = 0; q < 5; ++q) {
        float4 v = row[sub + q * 4];
        int c0 = (sub + q * 4) * 4;
        if (v.x > m) { m = v.x; lbl = c0 + 0; }
        if (v.y > m) { m = v.y; lbl = c0 + 1; }
        if (v.z > m) { m = v.z; lbl = c0 + 2; }
        if (v.w > m) { m = v.w; lbl = c0 + 3; }
    }

    unsigned int mb = __float_as_uint(m);
    mb ^= (mb & 0x80000000u) ? 0xFFFFFFFFu : 0x80000000u;
    unsigned long long key =
        ((unsigned long long)mb << 32) | (unsigned int)(0xFFFFFFFFu - (unsigned int)lbl);
#pragma unroll
    for (int d = 1; d < 4; d <<= 1) {
        unsigned long long o = __shfl_xor(key, d, 64);
        if (o > key) key = o;
    }
    if (sub != 0) return;

    unsigned int hb = (unsigned int)(key >> 32);
    hb ^= (hb & 0x80000000u) ? 0x80000000u : 0xFFFFFFFFu;
    m = __uint_as_float(hb);
    lbl = (int)(0xFFFFFFFFu - (unsigned int)(key & 0xFFFFFFFFu));

    float sig = 1.0f / (1.0f + expf(-m));
    if (!(sig > 0.2f)) return;

    float4 ab = ((const float4*)anc)[a];
    float4 rb = ((const float4*)reg)[a];
    float ya = __fmul_rn(__fadd_rn(ab.x, ab.z), 0.5f);
    float xa = __fmul_rn(__fadd_rn(ab.y, ab.w), 0.5f);
    float ha = __fsub_rn(ab.z, ab.x);
    float wa = __fsub_rn(ab.w, ab.y);
    float w = __fmul_rn(expf(rb.w), wa);
    float h = __fmul_rn(expf(rb.z), ha);
    float yc = __fadd_rn(__fmul_rn(rb.x, ha), ya);
    float xc = __fadd_rn(__fmul_rn(rb.y, wa), xa);
    float x1 = fmaxf(__fsub_rn(xc, __fmul_rn(w, 0.5f)), 0.0f);
    float y1 = fmaxf(__fsub_rn(yc, __fmul_rn(h, 0.5f)), 0.0f);
    float x2 = fminf(__fadd_rn(xc, __fmul_rn(w, 0.5f)), IMGF);
    float y2 = fminf(__fadd_rn(yc, __fmul_rn(h, 0.5f)), IMGF);

    int pos = atomicAdd(&ws->count, 1);
    if (pos < CAP) {
        ws->key[pos] = ((unsigned long long)__float_as_uint(sig) << 32) |
                       (unsigned int)(0xFFFFFFFFu - (unsigned int)a);
        ws->box[pos] = make_float4(x1, y1, x2, y2);
        ws->label[pos] = lbl;
    }
}

// Phase 2a: rank sort with LDS-staged keys (wave-uniform broadcast reads).
__global__ __launch_bounds__(256) void rank_kernel(Ws* __restrict__ ws) {
    __shared__ unsigned long long kl[CAP];
    int tid = threadIdx.x;
    int n = ws->count;
    if (n > CAP) n = CAP;

    for (int j = tid; j < n; j += 256) kl[j] = ws->key[j];
    __syncthreads();

    int i = blockIdx.x * 256 + tid;
    if (i >= n) return;

    unsigned long long my = kl[i];
    int r = 0;
    int j = 0;
    for (; j + 8 <= n; j += 8) {
        r += (kl[j + 0] > my) ? 1 : 0;
        r += (kl[j + 1] > my) ? 1 : 0;
        r += (kl[j + 2] > my) ? 1 : 0;
        r += (kl[j + 3] > my) ? 1 : 0;
        r += (kl[j + 4] > my) ? 1 : 0;
        r += (kl[j + 5] > my) ? 1 : 0;
        r += (kl[j + 6] > my) ? 1 : 0;
        r += (kl[j + 7] > my) ? 1 : 0;
    }
    for (; j < n; ++j) r += (kl[j] > my) ? 1 : 0;

    ws->skey[r] = my;
    ws->sbox[r] = ws->box[i];
    ws->slabel[r] = ws->label[i];
}

// Phase 2b: suppression bit-matrix. One wave per (row i, word w).
__global__ __launch_bounds__(256) void mask_kernel(Ws* __restrict__ ws) {
    int gw = (blockIdx.x * 256 + threadIdx.x) >> 6;
    int lane = threadIdx.x & 63;
    if (gw >= SWEEP_CAP * NW) return;
    int i = gw / NW;
    int w = gw - i * NW;
    int n = ws->count;
    if (n > CAP) n = CAP;
    if (n > SWEEP_CAP) n = SWEEP_CAP;
    if (i >= n) {
        if (lane == 0) ws->M[gw] = 0ull;
        return;
    }

    float4 kb = ws->sbox[i];  // uniform -> broadcast
    float ka = __fmul_rn(__fsub_rn(kb.z, kb.x), __fsub_rn(kb.w, kb.y));
    int j = (w << 6) | lane;
    float4 cb = ws->sbox[j];  // coalesced
    float ca = __fmul_rn(__fsub_rn(cb.z, cb.x), __fsub_rn(cb.w, cb.y));
    float ix1 = fmaxf(kb.x, cb.x);
    float iy1 = fmaxf(kb.y, cb.y);
    float ix2 = fminf(kb.z, cb.z);
    float iy2 = fminf(kb.w, cb.w);
    float iw = fmaxf(__fsub_rn(ix2, ix1), 0.0f);
    float ih = fmaxf(__fsub_rn(iy2, iy1), 0.0f);
    float inter = __fmul_rn(iw, ih);
    float denom = __fadd_rn(__fadd_rn(__fadd_rn(ka, ca), -inter), 1e-8f);
    float iou = __fdiv_rn(inter, denom);
    unsigned long long bal = __ballot(!(iou < IOU_T));
    if (lane == 0) ws->M[gw] = bal;
}

// Phase 2c: batch-speculative sweep. Collect the next 8 set bits (SALU only),
// issue all 8 M-row loads at once (one latency round trip), then verify/commit
// in order with a register-resident suppression union. P(spec correct per
// slot) ~ 99% (each keep suppresses ~1% of remaining candidates); mispredicted
// slots are skipped and their rows discarded. All slots are named scalars ->
// no dynamic indexing, no scratch.
__global__ __launch_bounds__(64, 1) void sweep_kernel(const Ws* __restrict__ ws,
                                                      float* __restrict__ out) {
    int lane = threadIdx.x;
    int n = ws->count;
    if (n > CAP) n = CAP;
    if (n > SWEEP_CAP) n = SWEEP_CAP;

    unsigned long long act;
    {
        int rem = n - (lane << 6);
        act = (rem >= 64) ? ~0ull : ((rem > 0) ? ((1ull << rem) - 1ull) : 0ull);
        if (lane >= NW) act = 0ull;
    }

    int k0 = 0, k1 = 0, nk = 0;
    int pos = -1;

    while (nk < MAX_DETS) {
        // ---- collect up to 8 set bits of act strictly greater than pos ----
        int c0 = 0, c1 = 0, c2 = 0, c3 = 0, c4 = 0, c5 = 0, c6 = 0, c7 = 0;
        int ncand = 0;
        int w0 = (pos + 1) >> 6;
        for (int w = w0; w < NW && ncand < 8; ++w) {
            unsigned int lo = __builtin_amdgcn_readlane((unsigned int)(act & 0xFFFFFFFFull), w);
            unsigned int hi = __builtin_amdgcn_readlane((unsigned int)(act >> 32), w);
            unsigned long long aw = ((unsigned long long)hi << 32) | lo;
            if (pos >= 0 && w == (pos >> 6)) aw &= ~((2ull << (pos & 63)) - 1ull);
            while (aw && ncand < 8) {
                int b = __builtin_ctzll(aw);
                aw &= aw - 1ull;
                int idx = (w << 6) | b;
                switch (ncand) {
                    case 0: c0 = idx; break;
                    case 1: c1 = idx; break;
                    case 2: c2 = idx; break;
                    case 3: c3 = idx; break;
                    case 4: c4 = idx; break;
                    case 5: c5 = idx; break;
                    case 6: c6 = idx; break;
                    default: c7 = idx; break;
                }
                ++ncand;
            }
        }
        if (ncand == 0) break;

        // ---- issue all 8 row loads back-to-back (independent addresses) ----
        unsigned long long r0 = 0, r1 = 0, r2 = 0, r3 = 0, r4 = 0, r5 = 0, r6 = 0, r7 = 0;
        if (lane < NW) {
            r0 = ws->M[(size_t)c0 * NW + lane];
            r1 = ws->M[(size_t)c1 * NW + lane];
            r2 = ws->M[(size_t)c2 * NW + lane];
            r3 = ws->M[(size_t)c3 * NW + lane];
            r4 = ws->M[(size_t)c4 * NW + lane];
            r5 = ws->M[(size_t)c5 * NW + lane];
            r6 = ws->M[(size_t)c6 * NW + lane];
            r7 = ws->M[(size_t)c7 * NW + lane];
        }

        // ---- verify & commit in sorted order ----
        unsigned long long sup = 0ull;
#define COMMIT(S, CS, RS)                                                                 \
        if (S < ncand && nk < MAX_DETS) {                                                 \
            unsigned int slo = __builtin_amdgcn_readlane((unsigned int)(sup & 0xFFFFFFFFull), (CS) >> 6); \
            unsigned int shi = __builtin_amdgcn_readlane((unsigned int)(sup >> 32), (CS) >> 6);           \
            unsigned long long sw = ((unsigned long long)shi << 32) | slo;                \
            if (!((sw >> ((CS) & 63)) & 1ull)) {                                          \
                if (nk < 64) { if (lane == nk) k0 = (CS); }                               \
                else         { if (lane == nk - 64) k1 = (CS); }                          \
                ++nk;                                                                     \
                sup |= (RS);                                                              \
            }                                                                             \
        }
        COMMIT(0, c0, r0)
        COMMIT(1, c1, r1)
        COMMIT(2, c2, r2)
        COMMIT(3, c3, r3)
        COMMIT(4, c4, r4)
        COMMIT(5, c5, r5)
        COMMIT(6, c6, r6)
        COMMIT(7, c7, r7)
#undef COMMIT
        act &= ~sup;

        switch (ncand) {
            case 1: pos = c0; break;
            case 2: pos = c1; break;
            case 3: pos = c2; break;
            case 4: pos = c3; break;
            case 5: pos = c4; break;
            case 6: pos = c5; break;
            case 7: pos = c6; break;
            default: pos = c7; break;
        }
    }

    // outputs: 100 boxes + 100 scores + 100 labels (zeros for invalid slots)
    for (int o = lane; o < MAX_DETS; o += 64) {
        float b0 = 0.f, b1 = 0.f, b2 = 0.f, b3 = 0.f, sc = 0.f, lb = 0.f;
        int pick = (o < 64) ? k0 : k1;
        if (o < nk) {
            float4 bb = ws->sbox[pick];
            b0 = bb.x; b1 = bb.y; b2 = bb.z; b3 = bb.w;
            sc = __uint_as_float((unsigned int)(ws->skey[pick] >> 32));
            lb = (float)ws->slabel[pick];
        }
        out[o * 4 + 0] = b0;
        out[o * 4 + 1] = b1;
        out[o * 4 + 2] = b2;
        out[o * 4 + 3] = b3;
        out[400 + o] = sc;
        out[500 + o] = lb;
    }
}

extern "C" void kernel_launch(void* const* d_in, const int* in_sizes, int n_in,
                              void* d_out, int out_size, void* d_ws, size_t ws_size,
                              hipStream_t stream) {
    const float* reg = (const float*)d_in[1];
    const float* cls = (const float*)d_in[2];
    const float* anc = (const float*)d_in[3];
    Ws* ws = (Ws*)d_ws;

    hipMemsetAsync(d_ws, 0, sizeof(int), stream);  // zero candidate count

    int blocks = (A_TOTAL * 4 + 255) / 256;
    score_decode_kernel<<<blocks, 256, 0, stream>>>(cls, reg, anc, ws);
    rank_kernel<<<CAP / 256, 256, 0, stream>>>(ws);
    mask_kernel<<<(SWEEP_CAP * NW + 3) / 4, 256, 0, stream>>>(ws);
    sweep_kernel<<<1, 64, 0, stream>>>(ws, (float*)d_out);
}

// Round 16
// 152.769 us; speedup vs baseline: 9.1288x; 1.0021x over previous
//
#include <hip/hip_runtime.h>
#include <hip/hip_bf16.h>

#define A_TOTAL 110484
#define NCLS 80
#define CAP 2048          // storage cap; n ~ 1330 expected
#define NW 26             // suppression words per row: 26*64 = 1664
#define SWEEP_CAP (NW * 64)
#define MAX_DETS 100
#define IMGF 768.0f
#define IOU_T 0.2f
#define APB 64                    // anchors per block (decode)
#define F4PB (APB * 20)           // 1280 float4s per block
#define TOT_F4 (A_TOTAL * 20)     // total float4s in cls

struct Ws {
    int count;
    int pad[3];
    unsigned long long key[CAP];   // unsorted: score_bits<<32 | ~anchor
    float4 box[CAP];
    int label[CAP];
    unsigned long long skey[CAP];  // sorted descending == argsort(-scores)
    float4 sbox[CAP];
    int slabel[CAP];
    unsigned long long M[SWEEP_CAP * NW];  // suppression bit-matrix (row-major)
};

// Phase 1 v3: flat-stream staging. Each block owns 64 complete rows (1280
// float4, contiguous); every wave-load is 4KB fully-coalesced. Per-f4
// (max,label) -> monotone u64 key -> LDS; 4 threads/anchor reduce 5 keys + 2
// shfl_xor. Key/tie-break scheme identical to the validated rounds (absmax 0.0).
__global__ __launch_bounds__(256) void score_decode_kernel(const float* __restrict__ cls,
                                                           const float* __restrict__ reg,
                                                           const float* __restrict__ anc,
                                                           Ws* __restrict__ ws) {
    __shared__ unsigned long long kl[F4PB];
    int tid = threadIdx.x;
    int base = blockIdx.x * F4PB;
    const float4* cf4 = (const float4*)cls;

#pragma unroll
    for (int k = 0; k < 5; ++k) {
        int fl = k * 256 + tid;          // 0..1279
        int f = base + fl;
        if (f < TOT_F4) {
            float4 v = cf4[f];
            // base % 20 == 0 (1280 % 20 == 0) -> quad index from fl alone
            int q = fl % 20;
            float m = v.x; int j = 0;
            if (v.y > m) { m = v.y; j = 1; }
            if (v.z > m) { m = v.z; j = 2; }
            if (v.w > m) { m = v.w; j = 3; }
            int c = q * 4 + j;
            unsigned int mb = __float_as_uint(m);
            mb ^= (mb & 0x80000000u) ? 0xFFFFFFFFu : 0x80000000u;  // monotone map
            kl[fl] = ((unsigned long long)mb << 32) |
                     (unsigned int)(0xFFFFFFFFu - (unsigned int)c);
        }
    }
    __syncthreads();

    int a = tid >> 2;          // local anchor 0..63
    int s = tid & 3;           // 4 threads per anchor
    int a_glob = blockIdx.x * APB + a;

    int idx0 = a * 20 + s * 5;
    unsigned long long key = kl[idx0];
    unsigned long long k1 = kl[idx0 + 1];
    unsigned long long k2 = kl[idx0 + 2];
    unsigned long long k3 = kl[idx0 + 3];
    unsigned long long k4 = kl[idx0 + 4];
    if (k1 > key) key = k1;
    if (k2 > key) key = k2;
    if (k3 > key) key = k3;
    if (k4 > key) key = k4;
#pragma unroll
    for (int d = 1; d < 4; d <<= 1) {
        unsigned long long o = __shfl_xor(key, d, 64);
        if (o > key) key = o;
    }
    if (s != 0 || a_glob >= A_TOTAL) return;

    unsigned int hb = (unsigned int)(key >> 32);
    hb ^= (hb & 0x80000000u) ? 0x80000000u : 0xFFFFFFFFu;   // inverse map
    float m = __uint_as_float(hb);
    int lbl = (int)(0xFFFFFFFFu - (unsigned int)(key & 0xFFFFFFFFu));

    float sig = 1.0f / (1.0f + expf(-m));
    if (!(sig > 0.2f)) return;

    float4 ab = ((const float4*)anc)[a_glob];
    float4 rb = ((const float4*)reg)[a_glob];
    float ya = __fmul_rn(__fadd_rn(ab.x, ab.z), 0.5f);
    float xa = __fmul_rn(__fadd_rn(ab.y, ab.w), 0.5f);
    float ha = __fsub_rn(ab.z, ab.x);
    float wa = __fsub_rn(ab.w, ab.y);
    float w = __fmul_rn(expf(rb.w), wa);
    float h = __fmul_rn(expf(rb.z), ha);
    float yc = __fadd_rn(__fmul_rn(rb.x, ha), ya);
    float xc = __fadd_rn(__fmul_rn(rb.y, wa), xa);
    float x1 = fmaxf(__fsub_rn(xc, __fmul_rn(w, 0.5f)), 0.0f);
    float y1 = fmaxf(__fsub_rn(yc, __fmul_rn(h, 0.5f)), 0.0f);
    float x2 = fminf(__fadd_rn(xc, __fmul_rn(w, 0.5f)), IMGF);
    float y2 = fminf(__fadd_rn(yc, __fmul_rn(h, 0.5f)), IMGF);

    int pos = atomicAdd(&ws->count, 1);
    if (pos < CAP) {
        ws->key[pos] = ((unsigned long long)__float_as_uint(sig) << 32) |
                       (unsigned int)(0xFFFFFFFFu - (unsigned int)a_glob);
        ws->box[pos] = make_float4(x1, y1, x2, y2);
        ws->label[pos] = lbl;
    }
}

// Phase 2a: rank sort with LDS-staged keys (wave-uniform broadcast reads).
__global__ __launch_bounds__(256) void rank_kernel(Ws* __restrict__ ws) {
    __shared__ unsigned long long kl[CAP];
    int tid = threadIdx.x;
    int n = ws->count;
    if (n > CAP) n = CAP;

    for (int j = tid; j < n; j += 256) kl[j] = ws->key[j];
    __syncthreads();

    int i = blockIdx.x * 256 + tid;
    if (i >= n) return;

    unsigned long long my = kl[i];
    int r = 0;
    int j = 0;
    for (; j + 8 <= n; j += 8) {
        r += (kl[j + 0] > my) ? 1 : 0;
        r += (kl[j + 1] > my) ? 1 : 0;
        r += (kl[j + 2] > my) ? 1 : 0;
        r += (kl[j + 3] > my) ? 1 : 0;
        r += (kl[j + 4] > my) ? 1 : 0;
        r += (kl[j + 5] > my) ? 1 : 0;
        r += (kl[j + 6] > my) ? 1 : 0;
        r += (kl[j + 7] > my) ? 1 : 0;
    }
    for (; j < n; ++j) r += (kl[j] > my) ? 1 : 0;

    ws->skey[r] = my;
    ws->sbox[r] = ws->box[i];
    ws->slabel[r] = ws->label[i];
}

// Phase 2b: suppression bit-matrix. One wave per (row i, word w).
__global__ __launch_bounds__(256) void mask_kernel(Ws* __restrict__ ws) {
    int gw = (blockIdx.x * 256 + threadIdx.x) >> 6;
    int lane = threadIdx.x & 63;
    if (gw >= SWEEP_CAP * NW) return;
    int i = gw / NW;
    int w = gw - i * NW;
    int n = ws->count;
    if (n > CAP) n = CAP;
    if (n > SWEEP_CAP) n = SWEEP_CAP;
    if (i >= n) {
        if (lane == 0) ws->M[gw] = 0ull;
        return;
    }

    float4 kb = ws->sbox[i];  // uniform -> broadcast
    float ka = __fmul_rn(__fsub_rn(kb.z, kb.x), __fsub_rn(kb.w, kb.y));
    int j = (w << 6) | lane;
    float4 cb = ws->sbox[j];  // coalesced
    float ca = __fmul_rn(__fsub_rn(cb.z, cb.x), __fsub_rn(cb.w, cb.y));
    float ix1 = fmaxf(kb.x, cb.x);
    float iy1 = fmaxf(kb.y, cb.y);
    float ix2 = fminf(kb.z, cb.z);
    float iy2 = fminf(kb.w, cb.w);
    float iw = fmaxf(__fsub_rn(ix2, ix1), 0.0f);
    float ih = fmaxf(__fsub_rn(iy2, iy1), 0.0f);
    float inter = __fmul_rn(iw, ih);
    float denom = __fadd_rn(__fadd_rn(__fadd_rn(ka, ca), -inter), 1e-8f);
    float iou = __fdiv_rn(inter, denom);
    unsigned long long bal = __ballot(!(iou < IOU_T));
    if (lane == 0) ws->M[gw] = bal;
}

// Phase 2c: batch-speculative sweep (unchanged from round 15, absmax 0.0).
__global__ __launch_bounds__(64, 1) void sweep_kernel(const Ws* __restrict__ ws,
                                                      float* __restrict__ out) {
    int lane = threadIdx.x;
    int n = ws->count;
    if (n > CAP) n = CAP;
    if (n > SWEEP_CAP) n = SWEEP_CAP;

    unsigned long long act;
    {
        int rem = n - (lane << 6);
        act = (rem >= 64) ? ~0ull : ((rem > 0) ? ((1ull << rem) - 1ull) : 0ull);
        if (lane >= NW) act = 0ull;
    }

    int k0 = 0, k1 = 0, nk = 0;
    int pos = -1;

    while (nk < MAX_DETS) {
        int c0 = 0, c1 = 0, c2 = 0, c3 = 0, c4 = 0, c5 = 0, c6 = 0, c7 = 0;
        int ncand = 0;
        int w0 = (pos + 1) >> 6;
        for (int w = w0; w < NW && ncand < 8; ++w) {
            unsigned int lo = __builtin_amdgcn_readlane((unsigned int)(act & 0xFFFFFFFFull), w);
            unsigned int hi = __builtin_amdgcn_readlane((unsigned int)(act >> 32), w);
            unsigned long long aw = ((unsigned long long)hi << 32) | lo;
            if (pos >= 0 && w == (pos >> 6)) aw &= ~((2ull << (pos & 63)) - 1ull);
            while (aw && ncand < 8) {
                int b = __builtin_ctzll(aw);
                aw &= aw - 1ull;
                int idx = (w << 6) | b;
                switch (ncand) {
                    case 0: c0 = idx; break;
                    case 1: c1 = idx; break;
                    case 2: c2 = idx; break;
                    case 3: c3 = idx; break;
                    case 4: c4 = idx; break;
                    case 5: c5 = idx; break;
                    case 6: c6 = idx; break;
                    default: c7 = idx; break;
                }
                ++ncand;
            }
        }
        if (ncand == 0) break;

        unsigned long long r0 = 0, r1 = 0, r2 = 0, r3 = 0, r4 = 0, r5 = 0, r6 = 0, r7 = 0;
        if (lane < NW) {
            r0 = ws->M[(size_t)c0 * NW + lane];
            r1 = ws->M[(size_t)c1 * NW + lane];
            r2 = ws->M[(size_t)c2 * NW + lane];
            r3 = ws->M[(size_t)c3 * NW + lane];
            r4 = ws->M[(size_t)c4 * NW + lane];
            r5 = ws->M[(size_t)c5 * NW + lane];
            r6 = ws->M[(size_t)c6 * NW + lane];
            r7 = ws->M[(size_t)c7 * NW + lane];
        }

        unsigned long long sup = 0ull;
#define COMMIT(S, CS, RS)                                                                 \
        if (S < ncand && nk < MAX_DETS) {                                                 \
            unsigned int slo = __builtin_amdgcn_readlane((unsigned int)(sup & 0xFFFFFFFFull), (CS) >> 6); \
            unsigned int shi = __builtin_amdgcn_readlane((unsigned int)(sup >> 32), (CS) >> 6);           \
            unsigned long long sw = ((unsigned long long)shi << 32) | slo;                \
            if (!((sw >> ((CS) & 63)) & 1ull)) {                                          \
                if (nk < 64) { if (lane == nk) k0 = (CS); }                               \
                else         { if (lane == nk - 64) k1 = (CS); }                          \
                ++nk;                                                                     \
                sup |= (RS);                                                              \
            }                                                                             \
        }
        COMMIT(0, c0, r0)
        COMMIT(1, c1, r1)
        COMMIT(2, c2, r2)
        COMMIT(3, c3, r3)
        COMMIT(4, c4, r4)
        COMMIT(5, c5, r5)
        COMMIT(6, c6, r6)
        COMMIT(7, c7, r7)
#undef COMMIT
        act &= ~sup;

        switch (ncand) {
            case 1: pos = c0; break;
            case 2: pos = c1; break;
            case 3: pos = c2; break;
            case 4: pos = c3; break;
            case 5: pos = c4; break;
            case 6: pos = c5; break;
            case 7: pos = c6; break;
            default: pos = c7; break;
        }
    }

    for (int o = lane; o < MAX_DETS; o += 64) {
        float b0 = 0.f, b1 = 0.f, b2 = 0.f, b3 = 0.f, sc = 0.f, lb = 0.f;
        int pick = (o < 64) ? k0 : k1;
        if (o < nk) {
            float4 bb = ws->sbox[pick];
            b0 = bb.x; b1 = bb.y; b2 = bb.z; b3 = bb.w;
            sc = __uint_as_float((unsigned int)(ws->skey[pick] >> 32));
            lb = (float)ws->slabel[pick];
        }
        out[o * 4 + 0] = b0;
        out[o * 4 + 1] = b1;
        out[o * 4 + 2] = b2;
        out[o * 4 + 3] = b3;
        out[400 + o] = sc;
        out[500 + o] = lb;
    }
}

extern "C" void kernel_launch(void* const* d_in, const int* in_sizes, int n_in,
                              void* d_out, int out_size, void* d_ws, size_t ws_size,
                              hipStream_t stream) {
    const float* reg = (const float*)d_in[1];
    const float* cls = (const float*)d_in[2];
    const float* anc = (const float*)d_in[3];
    Ws* ws = (Ws*)d_ws;

    hipMemsetAsync(d_ws, 0, sizeof(int), stream);  // zero candidate count

    int blocks = (A_TOTAL + APB - 1) / APB;
    score_decode_kernel<<<blocks, 256, 0, stream>>>(cls, reg, anc, ws);
    rank_kernel<<<CAP / 256, 256, 0, stream>>>(ws);
    mask_kernel<<<(SWEEP_CAP * NW + 3) / 4, 256, 0, stream>>>(ws);
    sweep_kernel<<<1, 64, 0, stream>>>(ws, (float*)d_out);
}